// Round 13
// baseline (446.546 us; speedup 1.0000x reference)
//
#include <hip/hip_runtime.h>
#include <hip/hip_bf16.h>

// ExpertODEEnsemble: E=8, D=64, H=512, B=32768.
// R13 = R12 (1 block/CU, 128-row tiles, LDS flag sync, M=64xN=128 wave tile)
//  + self-first staggered group order (wave w consumes g=(w+gi)&7: first group
//    is its OWN slabs -> zero wait; 8 waves fan out over 8 producers instead
//    of convoying on producer 0), staggered epi-wait targets, and no memset
//    (out fully written by plain stores).

typedef unsigned short ushort_t;
typedef unsigned int u32;
typedef unsigned long long u64;
typedef __attribute__((ext_vector_type(8))) short short8;
typedef __attribute__((ext_vector_type(4))) float floatx4;
typedef __attribute__((ext_vector_type(16))) float floatx16;
typedef __attribute__((ext_vector_type(4))) int intx4;

// ws layout (bytes); granule = 16 B = 8 bf16 along k
#define W1A_OFF 0u          // per e (65536 B): byte w*8192  + kc*2048 + ol*1024 + lane*16
#define W2A_OFF 524288u     // per e (524288B): byte w*65536 + kc*2048 + ol*1024 + lane*16
#define W3A_OFF 4718592u
#define W4A_OFF 8912896u    // per e (65536 B): byte o4*32768 + kc*1024 + lane*16
#define XB_OFF  9437184u    // x row-major bf16 [32768][64]
#define B1E_OFF 13631488u   // b1_eff fp32 [8][512]

// LDS layout (dynamic): act 32 slabs * 4224 B; x 4 slabs * 4224; flags.
#define X_OFF_L 135168
#define SYNC_OFF 152064     // kcp[8] then pub[8]
#define SMEM_SZ 152128

static __device__ __forceinline__ u32 pk2bf(float a, float b) {
  union { __hip_bfloat162 h; u32 u; } v;
  v.h = __float22bfloat162_rn(make_float2(a, b));
  return v.u;
}

static __device__ __forceinline__ float pade_tanh(float x) {
  float x2 = x * x;
  float num = __builtin_fmaf(x2, __builtin_fmaf(x2, 1.0f, 105.0f), 945.0f);
  float den = __builtin_fmaf(x2, __builtin_fmaf(x2, 15.0f, 420.0f), 945.0f);
  return x * num * __builtin_amdgcn_rcpf(den);
}

static __device__ __forceinline__ void ald16(const void* g, void* l) {
  __builtin_amdgcn_global_load_lds((__attribute__((address_space(1))) void*)g,
                                   (__attribute__((address_space(3))) void*)l,
                                   16, 0, 0);
}

static __device__ __forceinline__ floatx16 mfma32(short8 a, short8 b, floatx16 c) {
  return __builtin_amdgcn_mfma_f32_32x32x16_bf16(a, b, c, 0, 0, 0);
}

// spin until *p >= tgt (LDS flag; all lanes read same addr -> broadcast)
static __device__ __forceinline__ void waitge(const int* p, int tgt) {
  while (*(volatile const int*)p < tgt) __builtin_amdgcn_s_sleep(1);
  __asm__ __volatile__("" ::: "memory");
}

// publish: drain own LDS ops, then one lane bumps the counter
static __device__ __forceinline__ void bump(int* p, int lane) {
  __asm__ __volatile__("s_waitcnt lgkmcnt(0)" ::: "memory");
  if (lane == 0) atomicAdd(p, 1);
}

// ---------------- prep: one 16B dest granule per thread ----------------------
__global__ __launch_bounds__(256) void prep_kernel(
    const float* __restrict__ t, const float* __restrict__ x,
    const float* __restrict__ omega, const float* __restrict__ W1,
    const float* __restrict__ b1, const float* __restrict__ W2,
    const float* __restrict__ W3, const float* __restrict__ W4,
    char* __restrict__ ws) {
  int i = blockIdx.x * 256 + threadIdx.x;
  if (i < 32768) {                       // W1A (row stride 67 -> scalar reads)
    int e = i >> 12, rem = i & 4095, outr = rem >> 3, kg = rem & 7;
    int lane = (outr & 31) | ((kg & 1) << 5);
    int w = outr >> 6, ol = (outr >> 5) & 1, kc = kg >> 1;
    int dest = e * 4096 + ((w * 4 + kc) * 2 + ol) * 64 + lane;
    const float* s = W1 + (e * 512 + outr) * 67 + kg * 8;
    ((intx4*)(ws + W1A_OFF))[dest] = (intx4){
        (int)pk2bf(s[0], s[1]), (int)pk2bf(s[2], s[3]),
        (int)pk2bf(s[4], s[5]), (int)pk2bf(s[6], s[7])};
    return;
  }
  i -= 32768;
  if (i < 262144) {                      // W2A
    int e = i >> 15, rem = i & 32767, outr = rem >> 6, kg = rem & 63;
    int lane = (outr & 31) | ((kg & 1) << 5);
    int w = outr >> 6, ol = (outr >> 5) & 1, kc = kg >> 1;
    int dest = e * 32768 + ((w * 32 + kc) * 2 + ol) * 64 + lane;
    const floatx4* s = (const floatx4*)(W2 + ((e << 9) + outr) * 512 + (kg << 3));
    floatx4 lo = s[0], hi = s[1];
    ((intx4*)(ws + W2A_OFF))[dest] = (intx4){
        (int)pk2bf(lo[0], lo[1]), (int)pk2bf(lo[2], lo[3]),
        (int)pk2bf(hi[0], hi[1]), (int)pk2bf(hi[2], hi[3])};
    return;
  }
  i -= 262144;
  if (i < 262144) {                      // W3A
    int e = i >> 15, rem = i & 32767, outr = rem >> 6, kg = rem & 63;
    int lane = (outr & 31) | ((kg & 1) << 5);
    int w = outr >> 6, ol = (outr >> 5) & 1, kc = kg >> 1;
    int dest = e * 32768 + ((w * 32 + kc) * 2 + ol) * 64 + lane;
    const floatx4* s = (const floatx4*)(W3 + ((e << 9) + outr) * 512 + (kg << 3));
    floatx4 lo = s[0], hi = s[1];
    ((intx4*)(ws + W3A_OFF))[dest] = (intx4){
        (int)pk2bf(lo[0], lo[1]), (int)pk2bf(lo[2], lo[3]),
        (int)pk2bf(hi[0], hi[1]), (int)pk2bf(hi[2], hi[3])};
    return;
  }
  i -= 262144;
  if (i < 32768) {                       // W4A
    int e = i >> 12, rem = i & 4095, outr = rem >> 6, kg = rem & 63;
    int lane = (outr & 31) | ((kg & 1) << 5);
    int o4 = outr >> 5, kc = kg >> 1;
    int dest = e * 4096 + (o4 * 32 + kc) * 64 + lane;
    const floatx4* s = (const floatx4*)(W4 + ((e << 6) + outr) * 512 + (kg << 3));
    floatx4 lo = s[0], hi = s[1];
    ((intx4*)(ws + W4A_OFF))[dest] = (intx4){
        (int)pk2bf(lo[0], lo[1]), (int)pk2bf(lo[2], lo[3]),
        (int)pk2bf(hi[0], hi[1]), (int)pk2bf(hi[2], hi[3])};
    return;
  }
  i -= 32768;
  if (i < 262144) {                      // x -> bf16
    const floatx4* s = (const floatx4*)(x + i * 8);
    floatx4 lo = s[0], hi = s[1];
    ((intx4*)(ws + XB_OFF))[i] = (intx4){
        (int)pk2bf(lo[0], lo[1]), (int)pk2bf(lo[2], lo[3]),
        (int)pk2bf(hi[0], hi[1]), (int)pk2bf(hi[2], hi[3])};
    return;
  }
  i -= 262144;
  if (i < 4096) {                        // b1_eff
    float tv = t[0];
    int e = i >> 9;
    float om = omega[e];
    ((float*)(ws + B1E_OFF))[i] = b1[i] + tv * W1[i * 67 + 64]
        + sinf(om * tv) * W1[i * 67 + 65] + cosf(om * tv) * W1[i * 67 + 66];
  }
}

// act (128 rows): slab kc (stride 4224 B); within: nt*1024 + ((koct&1)*32+r31)*16.
// Group = 4 consecutive kc slabs, produced by one wave per layer.

template <int NKC, bool ISX>
static __device__ __forceinline__ void mlp_layer(
    const char* __restrict__ bsrc, char* __restrict__ act,
    int* kcp, int* pub, int lane, int w, int q1, int r31,
    const char* __restrict__ Abase, const float* __restrict__ bias,
    int pub_tgt, int epi_base, bool epi_stagger, bool do_epi_wait) {
  const int voff = lane * 16;
  const char* Aw = Abase + w * (NKC * 2048) + voff;
  const int NG = NKC / 4;

  floatx16 acc[2][4];
#pragma unroll
  for (int ol = 0; ol < 2; ++ol) {
    int fe0 = w * 64 + ol * 32 + 4 * q1;
#pragma unroll
    for (int g = 0; g < 4; ++g) {
      floatx4 bv = *(const floatx4*)(bias + fe0 + 8 * g);
#pragma unroll
      for (int nt = 0; nt < 4; ++nt) {
        acc[ol][nt][4 * g + 0] = bv[0];
        acc[ol][nt][4 * g + 1] = bv[1];
        acc[ol][nt][4 * g + 2] = bv[2];
        acc[ol][nt][4 * g + 3] = bv[3];
      }
    }
  }
  const int g0 = w & (NG - 1);           // own group first: zero wait
  short8 a0 = *(const short8*)(Aw + g0 * 8192);
  short8 a1 = *(const short8*)(Aw + g0 * 8192 + 1024);

#pragma unroll 1
  for (int gi = 0; gi < NG; ++gi) {
    const int g = (w + gi) & (NG - 1);
    if (!ISX) waitge(pub + g, pub_tgt);
    const char* gb = bsrc + g * (4 * 4224) + voff;
    short8 b0 = *(const short8*)(gb);
    short8 b1v = *(const short8*)(gb + 1024);
    short8 b2 = *(const short8*)(gb + 2048);
    short8 b3 = *(const short8*)(gb + 3072);
    const char* Ag = Aw + g * 8192;
    const char* An = Aw + (((w + gi + 1) & (NG - 1)) * 8192);
#pragma unroll
    for (int j = 0; j < 4; ++j) {
      const char* ap = (j < 3) ? (Ag + (j + 1) * 2048) : An;
      short8 an0 = *(const short8*)(ap);
      short8 an1 = *(const short8*)(ap + 1024);
      const char* bn = gb + ((j + 1) & 3) * 4224;  // wrap inside group (flag-safe)
      short8 bn0 = *(const short8*)(bn);
      short8 bn1 = *(const short8*)(bn + 1024);
      short8 bn2 = *(const short8*)(bn + 2048);
      short8 bn3 = *(const short8*)(bn + 3072);
      acc[0][0] = mfma32(a0, b0, acc[0][0]);
      acc[0][1] = mfma32(a0, b1v, acc[0][1]);
      acc[0][2] = mfma32(a0, b2, acc[0][2]);
      acc[0][3] = mfma32(a0, b3, acc[0][3]);
      acc[1][0] = mfma32(a1, b0, acc[1][0]);
      acc[1][1] = mfma32(a1, b1v, acc[1][1]);
      acc[1][2] = mfma32(a1, b2, acc[1][2]);
      acc[1][3] = mfma32(a1, b3, acc[1][3]);
      a0 = an0; a1 = an1;
      b0 = bn0; b1v = bn1; b2 = bn2; b3 = bn3;
    }
    bump(kcp + w, lane);                 // finished reading group g this layer
  }

  // wait until no wave still reads my act slabs, then overwrite them
  if (do_epi_wait) {
    if (epi_stagger) {
      for (int w2 = 0; w2 < 8; ++w2)
        waitge(kcp + w2, epi_base + ((w - w2) & 7));
    } else {
      for (int w2 = 0; w2 < 8; ++w2) waitge(kcp + w2, epi_base);
    }
  }
#pragma unroll
  for (int ol = 0; ol < 2; ++ol) {
#pragma unroll
    for (int g = 0; g < 4; ++g) {
      int ko = ol * 4 + g;               // global koct = 8w + ko
      char* base = act + (4 * w + (ko >> 1)) * 4224
                   + (((ko & 1) * 32 + r31) << 4) + q1 * 8;
#pragma unroll
      for (int nt = 0; nt < 4; ++nt) {
        float v0 = pade_tanh(acc[ol][nt][4 * g + 0]);
        float v1 = pade_tanh(acc[ol][nt][4 * g + 1]);
        float v2 = pade_tanh(acc[ol][nt][4 * g + 2]);
        float v3 = pade_tanh(acc[ol][nt][4 * g + 3]);
        u32 lo = pk2bf(v0, v1), hi = pk2bf(v2, v3);
        *(u64*)(base + nt * 1024) = ((u64)hi << 32) | lo;
      }
    }
  }
  bump(pub + w, lane);                   // slabs published
}

extern "C" __global__ __launch_bounds__(512) void fused_kernel(
    const char* __restrict__ ws, const float* __restrict__ b2,
    const float* __restrict__ b3, const float* __restrict__ b4,
    const float* __restrict__ ew, float* __restrict__ out) {
  extern __shared__ char smem[];
  char* act = smem;
  char* xreg = smem + X_OFF_L;
  int* kcp = (int*)(smem + SYNC_OFF);
  int* pub = kcp + 8;

  const int t = threadIdx.x, lane = t & 63, w = t >> 6;   // 8 waves
  const int q1 = lane >> 5, r31 = lane & 31;
  const int row0 = blockIdx.x << 7;      // 128-row tile, 256 blocks (1/CU)
  const int voff = lane * 16;

  if (t < 16) ((int*)(smem + SYNC_OFF))[t] = 0;

  // stage x: 16 units of 1KB; unit u: x-slab u>>2, nt u&3
  const ushort_t* xb = (const ushort_t*)(ws + XB_OFF);
#pragma unroll
  for (int s = 0; s < 2; ++s) {
    int u = w + 8 * s, v = u >> 2, nt = u & 3;
    ald16(xb + (row0 + nt * 32 + r31) * 64 + (2 * v + q1) * 8,
          xreg + v * 4224 + nt * 1024);
  }
  __syncthreads();                       // x staged + flags zeroed

  const int rt = w & 3, kh = w >> 2;     // L4: row-tile, K-half
  const int row_l4 = row0 + rt * 32 + r31;
  floatx16 oacc[2] = {};

  for (int e = 0; e < 8; ++e) {
    // L1: reads x only; epi waits for ALL waves done with prev expert
    mlp_layer<4, true>(xreg, act, kcp, pub, lane, w, q1, r31,
                       ws + W1A_OFF + e * 65536,
                       (const float*)(ws + B1E_OFF) + e * 512,
                       0, 21 * e, false, e > 0);
    // L2: needs L1 slabs (pub >= 3e+1); epi: v consumed my L2-group at
    // kcp[v] = 21e + 2 + ((w-v)&7)
    mlp_layer<32, false>(act, act, kcp, pub, lane, w, q1, r31,
                         ws + W2A_OFF + e * 524288, b2 + e * 512,
                         3 * e + 1, 21 * e + 2, true, true);
    // L3: needs L2 slabs (pub >= 3e+2); epi base 21e+10
    mlp_layer<32, false>(act, act, kcp, pub, lane, w, q1, r31,
                         ws + W3A_OFF + e * 524288, b3 + e * 512,
                         3 * e + 2, 21 * e + 10, true, true);

    // L4: M=64 (both o4), N=32 (rows rt), K-half kh; staggered own-first
    {
      const char* spA = ws + W4A_OFF + e * 65536 + voff;
      const float sc = ew[row_l4 * 8 + e];
      floatx16 acc4[2] = {};
      const int gfirst = kh * 4 + rt;    // own group
      short8 a0 = *(const short8*)(spA + (gfirst * 4) * 1024);
      short8 a1 = *(const short8*)(spA + 32768 + (gfirst * 4) * 1024);
#pragma unroll 1
      for (int gl = 0; gl < 4; ++gl) {
        const int g = kh * 4 + ((rt + gl) & 3);
        waitge(pub + g, 3 * e + 3);
        const char* gb = act + g * (4 * 4224) + rt * 1024 + voff;
        short8 b = *(const short8*)(gb);
        const int gnext = kh * 4 + ((rt + gl + 1) & 3);
#pragma unroll
        for (int j = 0; j < 4; ++j) {
          const int kcn = (j < 3) ? (g * 4 + j + 1) : (gnext * 4);
          short8 an0 = *(const short8*)(spA + kcn * 1024);
          short8 an1 = *(const short8*)(spA + 32768 + kcn * 1024);
          short8 bn = *(const short8*)(gb + ((j + 1) & 3) * 4224);
          acc4[0] = mfma32(a0, b, acc4[0]);
          acc4[1] = mfma32(a1, b, acc4[1]);
          a0 = an0; a1 = an1; b = bn;
        }
        bump(kcp + w, lane);
      }
      if (kh == 0) {
        const float* bp = b4 + e * 64;
#pragma unroll
        for (int ol = 0; ol < 2; ++ol) {
          int fe0 = ol * 32 + 4 * q1;
#pragma unroll
          for (int g = 0; g < 4; ++g) {
            floatx4 bv = *(const floatx4*)(bp + fe0 + 8 * g);
            oacc[ol][4 * g + 0] += sc * (acc4[ol][4 * g + 0] + bv[0]);
            oacc[ol][4 * g + 1] += sc * (acc4[ol][4 * g + 1] + bv[1]);
            oacc[ol][4 * g + 2] += sc * (acc4[ol][4 * g + 2] + bv[2]);
            oacc[ol][4 * g + 3] += sc * (acc4[ol][4 * g + 3] + bv[3]);
          }
        }
      } else {
#pragma unroll
        for (int ol = 0; ol < 2; ++ol)
#pragma unroll
          for (int i = 0; i < 16; ++i) oacc[ol][i] += sc * acc4[ol][i];
      }
    }
  }

  // final: merge K-half partners (w, w+4) via LDS (act dead), plain stores
  __syncthreads();
  if (kh == 1) {
#pragma unroll
    for (int ol = 0; ol < 2; ++ol)
#pragma unroll
      for (int g = 0; g < 4; ++g) {
        floatx4 p = {oacc[ol][4 * g + 0], oacc[ol][4 * g + 1],
                     oacc[ol][4 * g + 2], oacc[ol][4 * g + 3]};
        *(floatx4*)(act + rt * 8192 + ol * 4096 + g * 1024 + lane * 16) = p;
      }
  }
  __syncthreads();
  if (kh == 0) {
    float* orow = out + row_l4 * 64;
#pragma unroll
    for (int ol = 0; ol < 2; ++ol)
#pragma unroll
      for (int g = 0; g < 4; ++g) {
        floatx4 p = *(const floatx4*)(act + rt * 8192 + ol * 4096 + g * 1024 + lane * 16);
        floatx4 v = {oacc[ol][4 * g + 0] + p[0], oacc[ol][4 * g + 1] + p[1],
                     oacc[ol][4 * g + 2] + p[2], oacc[ol][4 * g + 3] + p[3]};
        *(floatx4*)(orow + ol * 32 + 8 * g + 4 * q1) = v;
      }
  }
}

extern "C" void kernel_launch(void* const* d_in, const int* in_sizes, int n_in,
                              void* d_out, int out_size, void* d_ws, size_t ws_size,
                              hipStream_t stream) {
  const float* t  = (const float*)d_in[0];
  const float* x  = (const float*)d_in[1];
  const float* ew = (const float*)d_in[2];
  const float* om = (const float*)d_in[3];
  const float* W1 = (const float*)d_in[4];
  const float* b1 = (const float*)d_in[5];
  const float* W2 = (const float*)d_in[6];
  const float* b2 = (const float*)d_in[7];
  const float* W3 = (const float*)d_in[8];
  const float* b3 = (const float*)d_in[9];
  const float* W4 = (const float*)d_in[10];
  const float* b4 = (const float*)d_in[11];
  char* ws = (char*)d_ws;
  float* out = (float*)d_out;
  (void)in_sizes; (void)n_in; (void)ws_size; (void)out_size;

  static int smem_set = 0;
  if (!smem_set) {
    hipFuncSetAttribute((const void*)fused_kernel,
                        hipFuncAttributeMaxDynamicSharedMemorySize, SMEM_SZ);
    smem_set = 1;
  }
  // no memset: fused_kernel writes every element of out with plain stores
  // dest-granule threads: 32768+262144+262144+32768+262144+4096 = 856064
  prep_kernel<<<3344, 256, 0, stream>>>(t, x, om, W1, b1, W2, W3, W4, ws);
  fused_kernel<<<256, 512, SMEM_SZ, stream>>>(ws, b2, b3, b4, ew, out);
}

// Round 14
// 436.181 us; speedup vs baseline: 1.0238x; 1.0238x over previous
//
#include <hip/hip_runtime.h>
#include <hip/hip_bf16.h>

// ExpertODEEnsemble: E=8, D=64, H=512, B=32768.
// R14 = R12 (1 block/CU, 128-row tiles, LDS flag sync, M=64xN=128 wave tile,
// sequential group order 0..7 -- R13's stagger regressed and is reverted) +
//   (1) pk-packed (v_pk_fma_f32) Pade-tanh epilogue: epilogue VALU ~halves;
//       at 2 waves/SIMD the epilogue is critical-path (R11 showed the
//       VALUBusy drop; R12's occupancy makes it convert to time),
//   (2) dest-coalesced prep: thread == dest granule, lane-fastest -> 1KB/wave
//       coalesced writes; lanes L,L+32 share one 64B source line.

typedef unsigned short ushort_t;
typedef unsigned int u32;
typedef unsigned long long u64;
typedef __attribute__((ext_vector_type(8))) short short8;
typedef __attribute__((ext_vector_type(2))) float floatx2;
typedef __attribute__((ext_vector_type(4))) float floatx4;
typedef __attribute__((ext_vector_type(16))) float floatx16;
typedef __attribute__((ext_vector_type(4))) int intx4;

// ws layout (bytes); granule = 16 B = 8 bf16 along k
#define W1A_OFF 0u          // per e (65536 B): granule ((w*4+kc)*2+ol)*64+lane
#define W2A_OFF 524288u     // per e (524288B): granule ((w*32+kc)*2+ol)*64+lane
#define W3A_OFF 4718592u
#define W4A_OFF 8912896u    // per e (65536 B): granule (o4*32+kc)*64+lane
#define XB_OFF  9437184u    // x row-major bf16 [32768][64]
#define B1E_OFF 13631488u   // b1_eff fp32 [8][512]

// LDS layout (dynamic): act 32 slabs * 4224 B; x 4 slabs * 4224; flags.
#define X_OFF_L 135168
#define SYNC_OFF 152064     // kcp[8] then pub[8]
#define SMEM_SZ 152128

static __device__ __forceinline__ u32 pk2bf(float a, float b) {
  union { __hip_bfloat162 h; u32 u; } v;
  v.h = __float22bfloat162_rn(make_float2(a, b));
  return v.u;
}

static __device__ __forceinline__ floatx2 pade_tanh2(floatx2 x) {
  // tanh x = x(945+105x^2+x^4)/(945+420x^2+15x^4); |err|<=1e-4 for |x|<=2
  floatx2 x2 = x * x;
  floatx2 num = x2 * (x2 + 105.0f) + 945.0f;
  floatx2 den = x2 * (x2 * 15.0f + 420.0f) + 945.0f;
  floatx2 r;
  r[0] = __builtin_amdgcn_rcpf(den[0]);
  r[1] = __builtin_amdgcn_rcpf(den[1]);
  return x * num * r;
}

static __device__ __forceinline__ void ald16(const void* g, void* l) {
  __builtin_amdgcn_global_load_lds((__attribute__((address_space(1))) void*)g,
                                   (__attribute__((address_space(3))) void*)l,
                                   16, 0, 0);
}

static __device__ __forceinline__ floatx16 mfma32(short8 a, short8 b, floatx16 c) {
  return __builtin_amdgcn_mfma_f32_32x32x16_bf16(a, b, c, 0, 0, 0);
}

// spin until *p >= tgt (LDS flag; all lanes read same addr -> broadcast)
static __device__ __forceinline__ void waitge(const int* p, int tgt) {
  while (*(volatile const int*)p < tgt) __builtin_amdgcn_s_sleep(1);
  __asm__ __volatile__("" ::: "memory");
}

// publish: drain own LDS ops, then one lane bumps the counter
static __device__ __forceinline__ void bump(int* p, int lane) {
  __asm__ __volatile__("s_waitcnt lgkmcnt(0)" ::: "memory");
  if (lane == 0) atomicAdd(p, 1);
}

// ------ prep: thread == dest granule (lane-fastest) -> coalesced writes ------
__global__ __launch_bounds__(256) void prep_kernel(
    const float* __restrict__ t, const float* __restrict__ x,
    const float* __restrict__ omega, const float* __restrict__ W1,
    const float* __restrict__ b1, const float* __restrict__ W2,
    const float* __restrict__ W3, const float* __restrict__ W4,
    char* __restrict__ ws) {
  int i = blockIdx.x * 256 + threadIdx.x;
  if (i < 32768) {                       // W1A: d=((w*4+kc)*2+ol)*64+lane
    int e = i >> 12, d = i & 4095;
    int lane = d & 63, q = d >> 6;
    int ol = q & 1, kc = (q >> 1) & 3, w = q >> 3;
    int outr = w * 64 + ol * 32 + (lane & 31);
    int kg = kc * 2 + (lane >> 5);
    const float* s = W1 + (e * 512 + outr) * 67 + kg * 8;   // stride 67: scalar
    ((intx4*)(ws + W1A_OFF))[i] = (intx4){
        (int)pk2bf(s[0], s[1]), (int)pk2bf(s[2], s[3]),
        (int)pk2bf(s[4], s[5]), (int)pk2bf(s[6], s[7])};
    return;
  }
  i -= 32768;
  if (i < 262144) {                      // W2A: d=((w*32+kc)*2+ol)*64+lane
    int e = i >> 15, d = i & 32767;
    int lane = d & 63, q = d >> 6;
    int ol = q & 1, kc = (q >> 1) & 31, w = q >> 6;
    int outr = w * 64 + ol * 32 + (lane & 31);
    int kg = kc * 2 + (lane >> 5);
    const floatx4* s = (const floatx4*)(W2 + ((e << 9) + outr) * 512 + (kg << 3));
    floatx4 lo = s[0], hi = s[1];
    ((intx4*)(ws + W2A_OFF))[i] = (intx4){
        (int)pk2bf(lo[0], lo[1]), (int)pk2bf(lo[2], lo[3]),
        (int)pk2bf(hi[0], hi[1]), (int)pk2bf(hi[2], hi[3])};
    return;
  }
  i -= 262144;
  if (i < 262144) {                      // W3A
    int e = i >> 15, d = i & 32767;
    int lane = d & 63, q = d >> 6;
    int ol = q & 1, kc = (q >> 1) & 31, w = q >> 6;
    int outr = w * 64 + ol * 32 + (lane & 31);
    int kg = kc * 2 + (lane >> 5);
    const floatx4* s = (const floatx4*)(W3 + ((e << 9) + outr) * 512 + (kg << 3));
    floatx4 lo = s[0], hi = s[1];
    ((intx4*)(ws + W3A_OFF))[i] = (intx4){
        (int)pk2bf(lo[0], lo[1]), (int)pk2bf(lo[2], lo[3]),
        (int)pk2bf(hi[0], hi[1]), (int)pk2bf(hi[2], hi[3])};
    return;
  }
  i -= 262144;
  if (i < 32768) {                       // W4A: d=(o4*32+kc)*64+lane
    int e = i >> 12, d = i & 4095;
    int lane = d & 63, q = d >> 6;
    int kc = q & 31, o4 = q >> 5;
    int outr = o4 * 32 + (lane & 31);
    int kg = kc * 2 + (lane >> 5);
    const floatx4* s = (const floatx4*)(W4 + ((e << 6) + outr) * 512 + (kg << 3));
    floatx4 lo = s[0], hi = s[1];
    ((intx4*)(ws + W4A_OFF))[i] = (intx4){
        (int)pk2bf(lo[0], lo[1]), (int)pk2bf(lo[2], lo[3]),
        (int)pk2bf(hi[0], hi[1]), (int)pk2bf(hi[2], hi[3])};
    return;
  }
  i -= 32768;
  if (i < 262144) {                      // x -> bf16 (coalesced both ways)
    const floatx4* s = (const floatx4*)(x + i * 8);
    floatx4 lo = s[0], hi = s[1];
    ((intx4*)(ws + XB_OFF))[i] = (intx4){
        (int)pk2bf(lo[0], lo[1]), (int)pk2bf(lo[2], lo[3]),
        (int)pk2bf(hi[0], hi[1]), (int)pk2bf(hi[2], hi[3])};
    return;
  }
  i -= 262144;
  if (i < 4096) {                        // b1_eff
    float tv = t[0];
    int e = i >> 9;
    float om = omega[e];
    ((float*)(ws + B1E_OFF))[i] = b1[i] + tv * W1[i * 67 + 64]
        + sinf(om * tv) * W1[i * 67 + 65] + cosf(om * tv) * W1[i * 67 + 66];
  }
}

// act (128 rows): slab kc (stride 4224 B); within: nt*1024 + ((koct&1)*32+r31)*16.

template <int NKC, bool ISX>
static __device__ __forceinline__ void mlp_layer(
    const char* __restrict__ bsrc, char* __restrict__ act,
    int* kcp, int* pub, int lane, int w, int q1, int r31,
    const char* __restrict__ Abase, const float* __restrict__ bias,
    int pub_tgt, int tgt_cov, int tgt_oth, int khm, bool do_epi_wait) {
  const int voff = lane * 16;
  const char* sp = Abase + w * (NKC * 2048) + voff;

  floatx16 acc[2][4];
#pragma unroll
  for (int ol = 0; ol < 2; ++ol) {
    int fe0 = w * 64 + ol * 32 + 4 * q1;
#pragma unroll
    for (int g = 0; g < 4; ++g) {
      floatx4 bv = *(const floatx4*)(bias + fe0 + 8 * g);
#pragma unroll
      for (int nt = 0; nt < 4; ++nt) {
        acc[ol][nt][4 * g + 0] = bv[0];
        acc[ol][nt][4 * g + 1] = bv[1];
        acc[ol][nt][4 * g + 2] = bv[2];
        acc[ol][nt][4 * g + 3] = bv[3];
      }
    }
  }
  short8 a0 = *(const short8*)(sp);
  short8 a1 = *(const short8*)(sp + 1024);
  sp += 2048;

  const int NG = NKC / 4;
#pragma unroll 1
  for (int g = 0; g < NG; ++g) {
    if (!ISX) waitge(pub + g, pub_tgt);
    const char* gb = bsrc + g * (4 * 4224) + voff;
    short8 b0 = *(const short8*)(gb);
    short8 b1v = *(const short8*)(gb + 1024);
    short8 b2 = *(const short8*)(gb + 2048);
    short8 b3 = *(const short8*)(gb + 3072);
#pragma unroll
    for (int j = 0; j < 4; ++j) {
      short8 an0 = *(const short8*)(sp);          // linear A prefetch; overrun in-ws
      short8 an1 = *(const short8*)(sp + 1024);
      sp += 2048;
      const char* bn = gb + ((j + 1) & 3) * 4224; // wrap inside group (flag-safe)
      short8 bn0 = *(const short8*)(bn);
      short8 bn1 = *(const short8*)(bn + 1024);
      short8 bn2 = *(const short8*)(bn + 2048);
      short8 bn3 = *(const short8*)(bn + 3072);
      acc[0][0] = mfma32(a0, b0, acc[0][0]);
      acc[0][1] = mfma32(a0, b1v, acc[0][1]);
      acc[0][2] = mfma32(a0, b2, acc[0][2]);
      acc[0][3] = mfma32(a0, b3, acc[0][3]);
      acc[1][0] = mfma32(a1, b0, acc[1][0]);
      acc[1][1] = mfma32(a1, b1v, acc[1][1]);
      acc[1][2] = mfma32(a1, b2, acc[1][2]);
      acc[1][3] = mfma32(a1, b3, acc[1][3]);
      a0 = an0; a1 = an1;
      b0 = bn0; b1v = bn1; b2 = bn2; b3 = bn3;
    }
    bump(kcp + w, lane);                 // this wave finished reading group g
  }

  // epilogue: wait until no wave still reads my act slabs, then overwrite
  if (do_epi_wait) {
    for (int w2 = 0; w2 < 8; ++w2)
      waitge(kcp + w2, ((w2 >> 2) == khm) ? tgt_cov : tgt_oth);
  }
#pragma unroll
  for (int ol = 0; ol < 2; ++ol) {
#pragma unroll
    for (int g = 0; g < 4; ++g) {
      int ko = ol * 4 + g;               // global koct = 8w + ko
      char* base = act + (4 * w + (ko >> 1)) * 4224
                   + (((ko & 1) * 32 + r31) << 4) + q1 * 8;
#pragma unroll
      for (int nt = 0; nt < 4; ++nt) {
        floatx2 p0 = {acc[ol][nt][4 * g + 0], acc[ol][nt][4 * g + 1]};
        floatx2 p1 = {acc[ol][nt][4 * g + 2], acc[ol][nt][4 * g + 3]};
        floatx2 t0 = pade_tanh2(p0);
        floatx2 t1 = pade_tanh2(p1);
        u32 lo = pk2bf(t0[0], t0[1]), hi = pk2bf(t1[0], t1[1]);
        *(u64*)(base + nt * 1024) = ((u64)hi << 32) | lo;
      }
    }
  }
  bump(pub + w, lane);                   // slab published
}

extern "C" __global__ __launch_bounds__(512) void fused_kernel(
    const char* __restrict__ ws, const float* __restrict__ b2,
    const float* __restrict__ b3, const float* __restrict__ b4,
    const float* __restrict__ ew, float* __restrict__ out) {
  extern __shared__ char smem[];
  char* act = smem;
  char* xreg = smem + X_OFF_L;
  int* kcp = (int*)(smem + SYNC_OFF);
  int* pub = kcp + 8;

  const int t = threadIdx.x, lane = t & 63, w = t >> 6;   // 8 waves
  const int q1 = lane >> 5, r31 = lane & 31;
  const int row0 = blockIdx.x << 7;      // 128-row tile, 256 blocks (1/CU)
  const int voff = lane * 16;

  if (t < 16) ((int*)(smem + SYNC_OFF))[t] = 0;

  // stage x: 16 units of 1KB; unit u: x-slab u>>2, nt u&3
  const ushort_t* xb = (const ushort_t*)(ws + XB_OFF);
#pragma unroll
  for (int s = 0; s < 2; ++s) {
    int u = w + 8 * s, v = u >> 2, nt = u & 3;
    ald16(xb + (row0 + nt * 32 + r31) * 64 + (2 * v + q1) * 8,
          xreg + v * 4224 + nt * 1024);
  }
  __syncthreads();                       // x staged + flags zeroed

  const int rt = w & 3, kh = w >> 2;     // L4: row-tile, K-half
  const int row_l4 = row0 + rt * 32 + r31;
  floatx16 oacc[2] = {};

  for (int e = 0; e < 8; ++e) {
    // L1: reads x (no pub wait); epi waits vs prev expert's L4 readers
    mlp_layer<4, true>(xreg, act, kcp, pub, lane, w, q1, r31,
                       ws + W1A_OFF + e * 65536,
                       (const float*)(ws + B1E_OFF) + e * 512,
                       0, 21 * e + (w & 3) - 3, 21 * e + w - 11, w >> 2, e > 0);
    // L2
    mlp_layer<32, false>(act, act, kcp, pub, lane, w, q1, r31,
                         ws + W2A_OFF + e * 524288, b2 + e * 512,
                         3 * e + 1, 21 * e + w + 2, 21 * e + w + 2, 0, true);
    // L3
    mlp_layer<32, false>(act, act, kcp, pub, lane, w, q1, r31,
                         ws + W3A_OFF + e * 524288, b3 + e * 512,
                         3 * e + 2, 21 * e + w + 10, 21 * e + w + 10, 0, true);

    // L4: M=64 (both o4 halves), N=32 (rows rt), K-half kh; no act writes
    {
      const char* spA = ws + W4A_OFF + e * 65536 + voff;
      const float sc = ew[row_l4 * 8 + e];
      floatx16 acc4[2] = {};
      int kc0 = kh * 16;
      short8 a0 = *(const short8*)(spA + kc0 * 1024);
      short8 a1 = *(const short8*)(spA + 32768 + kc0 * 1024);
#pragma unroll 1
      for (int gl = 0; gl < 4; ++gl) {
        int g = kh * 4 + gl;
        waitge(pub + g, 3 * e + 3);
        const char* gb = act + g * (4 * 4224) + rt * 1024 + voff;
        short8 b = *(const short8*)(gb);
#pragma unroll
        for (int j = 0; j < 4; ++j) {
          int kc = g * 4 + j;
          short8 an0 = *(const short8*)(spA + (kc + 1) * 1024);           // overrun in-ws
          short8 an1 = *(const short8*)(spA + 32768 + (kc + 1) * 1024);   // overrun in-ws
          short8 bn = *(const short8*)(gb + ((j + 1) & 3) * 4224);
          acc4[0] = mfma32(a0, b, acc4[0]);
          acc4[1] = mfma32(a1, b, acc4[1]);
          a0 = an0; a1 = an1; b = bn;
        }
        bump(kcp + w, lane);
      }
      if (kh == 0) {
        const float* bp = b4 + e * 64;
#pragma unroll
        for (int ol = 0; ol < 2; ++ol) {
          int fe0 = ol * 32 + 4 * q1;
#pragma unroll
          for (int g = 0; g < 4; ++g) {
            floatx4 bv = *(const floatx4*)(bp + fe0 + 8 * g);
            oacc[ol][4 * g + 0] += sc * (acc4[ol][4 * g + 0] + bv[0]);
            oacc[ol][4 * g + 1] += sc * (acc4[ol][4 * g + 1] + bv[1]);
            oacc[ol][4 * g + 2] += sc * (acc4[ol][4 * g + 2] + bv[2]);
            oacc[ol][4 * g + 3] += sc * (acc4[ol][4 * g + 3] + bv[3]);
          }
        }
      } else {
#pragma unroll
        for (int ol = 0; ol < 2; ++ol)
#pragma unroll
          for (int i = 0; i < 16; ++i) oacc[ol][i] += sc * acc4[ol][i];
      }
    }
  }

  // final: merge K-half partners (w, w+4) via LDS (act dead), plain stores
  __syncthreads();
  if (kh == 1) {
#pragma unroll
    for (int ol = 0; ol < 2; ++ol)
#pragma unroll
      for (int g = 0; g < 4; ++g) {
        floatx4 p = {oacc[ol][4 * g + 0], oacc[ol][4 * g + 1],
                     oacc[ol][4 * g + 2], oacc[ol][4 * g + 3]};
        *(floatx4*)(act + rt * 8192 + ol * 4096 + g * 1024 + lane * 16) = p;
      }
  }
  __syncthreads();
  if (kh == 0) {
    float* orow = out + row_l4 * 64;
#pragma unroll
    for (int ol = 0; ol < 2; ++ol)
#pragma unroll
      for (int g = 0; g < 4; ++g) {
        floatx4 p = *(const floatx4*)(act + rt * 8192 + ol * 4096 + g * 1024 + lane * 16);
        floatx4 v = {oacc[ol][4 * g + 0] + p[0], oacc[ol][4 * g + 1] + p[1],
                     oacc[ol][4 * g + 2] + p[2], oacc[ol][4 * g + 3] + p[3]};
        *(floatx4*)(orow + ol * 32 + 8 * g + 4 * q1) = v;
      }
  }
}

extern "C" void kernel_launch(void* const* d_in, const int* in_sizes, int n_in,
                              void* d_out, int out_size, void* d_ws, size_t ws_size,
                              hipStream_t stream) {
  const float* t  = (const float*)d_in[0];
  const float* x  = (const float*)d_in[1];
  const float* ew = (const float*)d_in[2];
  const float* om = (const float*)d_in[3];
  const float* W1 = (const float*)d_in[4];
  const float* b1 = (const float*)d_in[5];
  const float* W2 = (const float*)d_in[6];
  const float* b2 = (const float*)d_in[7];
  const float* W3 = (const float*)d_in[8];
  const float* b3 = (const float*)d_in[9];
  const float* W4 = (const float*)d_in[10];
  const float* b4 = (const float*)d_in[11];
  char* ws = (char*)d_ws;
  float* out = (float*)d_out;
  (void)in_sizes; (void)n_in; (void)ws_size; (void)out_size;

  static int smem_set = 0;
  if (!smem_set) {
    hipFuncSetAttribute((const void*)fused_kernel,
                        hipFuncAttributeMaxDynamicSharedMemorySize, SMEM_SZ);
    smem_set = 1;
  }
  // no memset: fused_kernel writes every element of out with plain stores
  // dest-granule threads: 32768+262144+262144+32768+262144+4096 = 856064
  prep_kernel<<<3344, 256, 0, stream>>>(t, x, om, W1, b1, W2, W3, W4, ws);
  fused_kernel<<<256, 512, SMEM_SZ, stream>>>(ws, b2, b3, b4, ew, out);
}

// Round 15
// 430.694 us; speedup vs baseline: 1.0368x; 1.0127x over previous
//
#include <hip/hip_runtime.h>
#include <hip/hip_bf16.h>

// ExpertODEEnsemble: E=8, D=64, H=512, B=32768.
// R15 = recombination of verified-best parts:
//   fused kernel = R12 verbatim (1 block/CU, 128-row tiles, LDS flag sync,
//     M=64xN=128 wave tile, sequential group order, SCALAR Pade epilogue —
//     R14's pk-packed epilogue regressed 377->414 and is reverted)
//   prep = R14's dest-coalesced version (gap 64 -> 22 us measured).

typedef unsigned short ushort_t;
typedef unsigned int u32;
typedef unsigned long long u64;
typedef __attribute__((ext_vector_type(8))) short short8;
typedef __attribute__((ext_vector_type(4))) float floatx4;
typedef __attribute__((ext_vector_type(16))) float floatx16;
typedef __attribute__((ext_vector_type(4))) int intx4;

// ws layout (bytes); granule = 16 B = 8 bf16 along k
#define W1A_OFF 0u          // per e (65536 B): granule ((w*4+kc)*2+ol)*64+lane
#define W2A_OFF 524288u     // per e (524288B): granule ((w*32+kc)*2+ol)*64+lane
#define W3A_OFF 4718592u
#define W4A_OFF 8912896u    // per e (65536 B): granule (o4*32+kc)*64+lane
#define XB_OFF  9437184u    // x row-major bf16 [32768][64]
#define B1E_OFF 13631488u   // b1_eff fp32 [8][512]

// LDS layout (dynamic): act 32 slabs * 4224 B; x 4 slabs * 4224; flags.
#define X_OFF_L 135168
#define SYNC_OFF 152064     // kcp[8] then pub[8]
#define SMEM_SZ 152128

static __device__ __forceinline__ u32 pk2bf(float a, float b) {
  union { __hip_bfloat162 h; u32 u; } v;
  v.h = __float22bfloat162_rn(make_float2(a, b));
  return v.u;
}

static __device__ __forceinline__ float pade_tanh(float x) {
  // tanh x = x(945+105x^2+x^4)/(945+420x^2+15x^4); |err|<=1e-4 for |x|<=2
  float x2 = x * x;
  float num = __builtin_fmaf(x2, __builtin_fmaf(x2, 1.0f, 105.0f), 945.0f);
  float den = __builtin_fmaf(x2, __builtin_fmaf(x2, 15.0f, 420.0f), 945.0f);
  return x * num * __builtin_amdgcn_rcpf(den);
}

static __device__ __forceinline__ void ald16(const void* g, void* l) {
  __builtin_amdgcn_global_load_lds((__attribute__((address_space(1))) void*)g,
                                   (__attribute__((address_space(3))) void*)l,
                                   16, 0, 0);
}

static __device__ __forceinline__ floatx16 mfma32(short8 a, short8 b, floatx16 c) {
  return __builtin_amdgcn_mfma_f32_32x32x16_bf16(a, b, c, 0, 0, 0);
}

// spin until *p >= tgt (LDS flag; all lanes read same addr -> broadcast)
static __device__ __forceinline__ void waitge(const int* p, int tgt) {
  while (*(volatile const int*)p < tgt) __builtin_amdgcn_s_sleep(1);
  __asm__ __volatile__("" ::: "memory");
}

// publish: drain own LDS ops, then one lane bumps the counter
static __device__ __forceinline__ void bump(int* p, int lane) {
  __asm__ __volatile__("s_waitcnt lgkmcnt(0)" ::: "memory");
  if (lane == 0) atomicAdd(p, 1);
}

// ------ prep: thread == dest granule (lane-fastest) -> coalesced writes ------
__global__ __launch_bounds__(256) void prep_kernel(
    const float* __restrict__ t, const float* __restrict__ x,
    const float* __restrict__ omega, const float* __restrict__ W1,
    const float* __restrict__ b1, const float* __restrict__ W2,
    const float* __restrict__ W3, const float* __restrict__ W4,
    char* __restrict__ ws) {
  int i = blockIdx.x * 256 + threadIdx.x;
  if (i < 32768) {                       // W1A: d=((w*4+kc)*2+ol)*64+lane
    int e = i >> 12, d = i & 4095;
    int lane = d & 63, q = d >> 6;
    int ol = q & 1, kc = (q >> 1) & 3, w = q >> 3;
    int outr = w * 64 + ol * 32 + (lane & 31);
    int kg = kc * 2 + (lane >> 5);
    const float* s = W1 + (e * 512 + outr) * 67 + kg * 8;   // stride 67: scalar
    ((intx4*)(ws + W1A_OFF))[i] = (intx4){
        (int)pk2bf(s[0], s[1]), (int)pk2bf(s[2], s[3]),
        (int)pk2bf(s[4], s[5]), (int)pk2bf(s[6], s[7])};
    return;
  }
  i -= 32768;
  if (i < 262144) {                      // W2A: d=((w*32+kc)*2+ol)*64+lane
    int e = i >> 15, d = i & 32767;
    int lane = d & 63, q = d >> 6;
    int ol = q & 1, kc = (q >> 1) & 31, w = q >> 6;
    int outr = w * 64 + ol * 32 + (lane & 31);
    int kg = kc * 2 + (lane >> 5);
    const floatx4* s = (const floatx4*)(W2 + ((e << 9) + outr) * 512 + (kg << 3));
    floatx4 lo = s[0], hi = s[1];
    ((intx4*)(ws + W2A_OFF))[i] = (intx4){
        (int)pk2bf(lo[0], lo[1]), (int)pk2bf(lo[2], lo[3]),
        (int)pk2bf(hi[0], hi[1]), (int)pk2bf(hi[2], hi[3])};
    return;
  }
  i -= 262144;
  if (i < 262144) {                      // W3A
    int e = i >> 15, d = i & 32767;
    int lane = d & 63, q = d >> 6;
    int ol = q & 1, kc = (q >> 1) & 31, w = q >> 6;
    int outr = w * 64 + ol * 32 + (lane & 31);
    int kg = kc * 2 + (lane >> 5);
    const floatx4* s = (const floatx4*)(W3 + ((e << 9) + outr) * 512 + (kg << 3));
    floatx4 lo = s[0], hi = s[1];
    ((intx4*)(ws + W3A_OFF))[i] = (intx4){
        (int)pk2bf(lo[0], lo[1]), (int)pk2bf(lo[2], lo[3]),
        (int)pk2bf(hi[0], hi[1]), (int)pk2bf(hi[2], hi[3])};
    return;
  }
  i -= 262144;
  if (i < 32768) {                       // W4A: d=(o4*32+kc)*64+lane
    int e = i >> 12, d = i & 4095;
    int lane = d & 63, q = d >> 6;
    int kc = q & 31, o4 = q >> 5;
    int outr = o4 * 32 + (lane & 31);
    int kg = kc * 2 + (lane >> 5);
    const floatx4* s = (const floatx4*)(W4 + ((e << 6) + outr) * 512 + (kg << 3));
    floatx4 lo = s[0], hi = s[1];
    ((intx4*)(ws + W4A_OFF))[i] = (intx4){
        (int)pk2bf(lo[0], lo[1]), (int)pk2bf(lo[2], lo[3]),
        (int)pk2bf(hi[0], hi[1]), (int)pk2bf(hi[2], hi[3])};
    return;
  }
  i -= 32768;
  if (i < 262144) {                      // x -> bf16 (coalesced both ways)
    const floatx4* s = (const floatx4*)(x + i * 8);
    floatx4 lo = s[0], hi = s[1];
    ((intx4*)(ws + XB_OFF))[i] = (intx4){
        (int)pk2bf(lo[0], lo[1]), (int)pk2bf(lo[2], lo[3]),
        (int)pk2bf(hi[0], hi[1]), (int)pk2bf(hi[2], hi[3])};
    return;
  }
  i -= 262144;
  if (i < 4096) {                        // b1_eff
    float tv = t[0];
    int e = i >> 9;
    float om = omega[e];
    ((float*)(ws + B1E_OFF))[i] = b1[i] + tv * W1[i * 67 + 64]
        + sinf(om * tv) * W1[i * 67 + 65] + cosf(om * tv) * W1[i * 67 + 66];
  }
}

// act (128 rows): slab kc (stride 4224 B); within: nt*1024 + ((koct&1)*32+r31)*16.

template <int NKC, bool ISX>
static __device__ __forceinline__ void mlp_layer(
    const char* __restrict__ bsrc, char* __restrict__ act,
    int* kcp, int* pub, int lane, int w, int q1, int r31,
    const char* __restrict__ Abase, const float* __restrict__ bias,
    int pub_tgt, int tgt_cov, int tgt_oth, int khm, bool do_epi_wait) {
  const int voff = lane * 16;
  const char* sp = Abase + w * (NKC * 2048) + voff;

  floatx16 acc[2][4];
#pragma unroll
  for (int ol = 0; ol < 2; ++ol) {
    int fe0 = w * 64 + ol * 32 + 4 * q1;
#pragma unroll
    for (int g = 0; g < 4; ++g) {
      floatx4 bv = *(const floatx4*)(bias + fe0 + 8 * g);
#pragma unroll
      for (int nt = 0; nt < 4; ++nt) {
        acc[ol][nt][4 * g + 0] = bv[0];
        acc[ol][nt][4 * g + 1] = bv[1];
        acc[ol][nt][4 * g + 2] = bv[2];
        acc[ol][nt][4 * g + 3] = bv[3];
      }
    }
  }
  short8 a0 = *(const short8*)(sp);
  short8 a1 = *(const short8*)(sp + 1024);
  sp += 2048;

  const int NG = NKC / 4;
#pragma unroll 1
  for (int g = 0; g < NG; ++g) {
    if (!ISX) waitge(pub + g, pub_tgt);
    const char* gb = bsrc + g * (4 * 4224) + voff;
    short8 b0 = *(const short8*)(gb);
    short8 b1v = *(const short8*)(gb + 1024);
    short8 b2 = *(const short8*)(gb + 2048);
    short8 b3 = *(const short8*)(gb + 3072);
#pragma unroll
    for (int j = 0; j < 4; ++j) {
      short8 an0 = *(const short8*)(sp);          // linear A prefetch; overrun in-ws
      short8 an1 = *(const short8*)(sp + 1024);
      sp += 2048;
      const char* bn = gb + ((j + 1) & 3) * 4224; // wrap inside group (flag-safe)
      short8 bn0 = *(const short8*)(bn);
      short8 bn1 = *(const short8*)(bn + 1024);
      short8 bn2 = *(const short8*)(bn + 2048);
      short8 bn3 = *(const short8*)(bn + 3072);
      acc[0][0] = mfma32(a0, b0, acc[0][0]);
      acc[0][1] = mfma32(a0, b1v, acc[0][1]);
      acc[0][2] = mfma32(a0, b2, acc[0][2]);
      acc[0][3] = mfma32(a0, b3, acc[0][3]);
      acc[1][0] = mfma32(a1, b0, acc[1][0]);
      acc[1][1] = mfma32(a1, b1v, acc[1][1]);
      acc[1][2] = mfma32(a1, b2, acc[1][2]);
      acc[1][3] = mfma32(a1, b3, acc[1][3]);
      a0 = an0; a1 = an1;
      b0 = bn0; b1v = bn1; b2 = bn2; b3 = bn3;
    }
    bump(kcp + w, lane);                 // this wave finished reading group g
  }

  // epilogue: wait until no wave still reads my act slabs, then overwrite
  if (do_epi_wait) {
    for (int w2 = 0; w2 < 8; ++w2)
      waitge(kcp + w2, ((w2 >> 2) == khm) ? tgt_cov : tgt_oth);
  }
#pragma unroll
  for (int ol = 0; ol < 2; ++ol) {
#pragma unroll
    for (int g = 0; g < 4; ++g) {
      int ko = ol * 4 + g;               // global koct = 8w + ko
      char* base = act + (4 * w + (ko >> 1)) * 4224
                   + (((ko & 1) * 32 + r31) << 4) + q1 * 8;
#pragma unroll
      for (int nt = 0; nt < 4; ++nt) {
        float v0 = pade_tanh(acc[ol][nt][4 * g + 0]);
        float v1 = pade_tanh(acc[ol][nt][4 * g + 1]);
        float v2 = pade_tanh(acc[ol][nt][4 * g + 2]);
        float v3 = pade_tanh(acc[ol][nt][4 * g + 3]);
        u32 lo = pk2bf(v0, v1), hi = pk2bf(v2, v3);
        *(u64*)(base + nt * 1024) = ((u64)hi << 32) | lo;
      }
    }
  }
  bump(pub + w, lane);                   // slab published
}

extern "C" __global__ __launch_bounds__(512) void fused_kernel(
    const char* __restrict__ ws, const float* __restrict__ b2,
    const float* __restrict__ b3, const float* __restrict__ b4,
    const float* __restrict__ ew, float* __restrict__ out) {
  extern __shared__ char smem[];
  char* act = smem;
  char* xreg = smem + X_OFF_L;
  int* kcp = (int*)(smem + SYNC_OFF);
  int* pub = kcp + 8;

  const int t = threadIdx.x, lane = t & 63, w = t >> 6;   // 8 waves
  const int q1 = lane >> 5, r31 = lane & 31;
  const int row0 = blockIdx.x << 7;      // 128-row tile, 256 blocks (1/CU)
  const int voff = lane * 16;

  if (t < 16) ((int*)(smem + SYNC_OFF))[t] = 0;

  // stage x: 16 units of 1KB; unit u: x-slab u>>2, nt u&3
  const ushort_t* xb = (const ushort_t*)(ws + XB_OFF);
#pragma unroll
  for (int s = 0; s < 2; ++s) {
    int u = w + 8 * s, v = u >> 2, nt = u & 3;
    ald16(xb + (row0 + nt * 32 + r31) * 64 + (2 * v + q1) * 8,
          xreg + v * 4224 + nt * 1024);
  }
  __syncthreads();                       // x staged + flags zeroed

  const int rt = w & 3, kh = w >> 2;     // L4: row-tile, K-half
  const int row_l4 = row0 + rt * 32 + r31;
  floatx16 oacc[2] = {};

  for (int e = 0; e < 8; ++e) {
    // L1: reads x (no pub wait); epi waits vs prev expert's L3/L4 readers
    mlp_layer<4, true>(xreg, act, kcp, pub, lane, w, q1, r31,
                       ws + W1A_OFF + e * 65536,
                       (const float*)(ws + B1E_OFF) + e * 512,
                       0, 21 * e + (w & 3) - 3, 21 * e + w - 11, w >> 2, e > 0);
    // L2
    mlp_layer<32, false>(act, act, kcp, pub, lane, w, q1, r31,
                         ws + W2A_OFF + e * 524288, b2 + e * 512,
                         3 * e + 1, 21 * e + w + 2, 21 * e + w + 2, 0, true);
    // L3
    mlp_layer<32, false>(act, act, kcp, pub, lane, w, q1, r31,
                         ws + W3A_OFF + e * 524288, b3 + e * 512,
                         3 * e + 2, 21 * e + w + 10, 21 * e + w + 10, 0, true);

    // L4: M=64 (both o4 halves), N=32 (rows rt), K-half kh; no act writes
    {
      const char* spA = ws + W4A_OFF + e * 65536 + voff;
      const float sc = ew[row_l4 * 8 + e];
      floatx16 acc4[2] = {};
      int kc0 = kh * 16;
      short8 a0 = *(const short8*)(spA + kc0 * 1024);
      short8 a1 = *(const short8*)(spA + 32768 + kc0 * 1024);
#pragma unroll 1
      for (int gl = 0; gl < 4; ++gl) {
        int g = kh * 4 + gl;
        waitge(pub + g, 3 * e + 3);
        const char* gb = act + g * (4 * 4224) + rt * 1024 + voff;
        short8 b = *(const short8*)(gb);
#pragma unroll
        for (int j = 0; j < 4; ++j) {
          int kc = g * 4 + j;
          short8 an0 = *(const short8*)(spA + (kc + 1) * 1024);           // overrun in-ws
          short8 an1 = *(const short8*)(spA + 32768 + (kc + 1) * 1024);   // overrun in-ws
          short8 bn = *(const short8*)(gb + ((j + 1) & 3) * 4224);
          acc4[0] = mfma32(a0, b, acc4[0]);
          acc4[1] = mfma32(a1, b, acc4[1]);
          a0 = an0; a1 = an1; b = bn;
        }
        bump(kcp + w, lane);
      }
      if (kh == 0) {
        const float* bp = b4 + e * 64;
#pragma unroll
        for (int ol = 0; ol < 2; ++ol) {
          int fe0 = ol * 32 + 4 * q1;
#pragma unroll
          for (int g = 0; g < 4; ++g) {
            floatx4 bv = *(const floatx4*)(bp + fe0 + 8 * g);
            oacc[ol][4 * g + 0] += sc * (acc4[ol][4 * g + 0] + bv[0]);
            oacc[ol][4 * g + 1] += sc * (acc4[ol][4 * g + 1] + bv[1]);
            oacc[ol][4 * g + 2] += sc * (acc4[ol][4 * g + 2] + bv[2]);
            oacc[ol][4 * g + 3] += sc * (acc4[ol][4 * g + 3] + bv[3]);
          }
        }
      } else {
#pragma unroll
        for (int ol = 0; ol < 2; ++ol)
#pragma unroll
          for (int i = 0; i < 16; ++i) oacc[ol][i] += sc * acc4[ol][i];
      }
    }
  }

  // final: merge K-half partners (w, w+4) via LDS (act dead), plain stores
  __syncthreads();
  if (kh == 1) {
#pragma unroll
    for (int ol = 0; ol < 2; ++ol)
#pragma unroll
      for (int g = 0; g < 4; ++g) {
        floatx4 p = {oacc[ol][4 * g + 0], oacc[ol][4 * g + 1],
                     oacc[ol][4 * g + 2], oacc[ol][4 * g + 3]};
        *(floatx4*)(act + rt * 8192 + ol * 4096 + g * 1024 + lane * 16) = p;
      }
  }
  __syncthreads();
  if (kh == 0) {
    float* orow = out + row_l4 * 64;
#pragma unroll
    for (int ol = 0; ol < 2; ++ol)
#pragma unroll
      for (int g = 0; g < 4; ++g) {
        floatx4 p = *(const floatx4*)(act + rt * 8192 + ol * 4096 + g * 1024 + lane * 16);
        floatx4 v = {oacc[ol][4 * g + 0] + p[0], oacc[ol][4 * g + 1] + p[1],
                     oacc[ol][4 * g + 2] + p[2], oacc[ol][4 * g + 3] + p[3]};
        *(floatx4*)(orow + ol * 32 + 8 * g + 4 * q1) = v;
      }
  }
}

extern "C" void kernel_launch(void* const* d_in, const int* in_sizes, int n_in,
                              void* d_out, int out_size, void* d_ws, size_t ws_size,
                              hipStream_t stream) {
  const float* t  = (const float*)d_in[0];
  const float* x  = (const float*)d_in[1];
  const float* ew = (const float*)d_in[2];
  const float* om = (const float*)d_in[3];
  const float* W1 = (const float*)d_in[4];
  const float* b1 = (const float*)d_in[5];
  const float* W2 = (const float*)d_in[6];
  const float* b2 = (const float*)d_in[7];
  const float* W3 = (const float*)d_in[8];
  const float* b3 = (const float*)d_in[9];
  const float* W4 = (const float*)d_in[10];
  const float* b4 = (const float*)d_in[11];
  char* ws = (char*)d_ws;
  float* out = (float*)d_out;
  (void)in_sizes; (void)n_in; (void)ws_size; (void)out_size;

  static int smem_set = 0;
  if (!smem_set) {
    hipFuncSetAttribute((const void*)fused_kernel,
                        hipFuncAttributeMaxDynamicSharedMemorySize, SMEM_SZ);
    smem_set = 1;
  }
  // no memset: fused_kernel writes every element of out with plain stores
  // dest-granule threads: 32768+262144+262144+32768+262144+4096 = 856064
  prep_kernel<<<3344, 256, 0, stream>>>(t, x, om, W1, b1, W2, W3, W4, ws);
  fused_kernel<<<256, 512, SMEM_SZ, stream>>>(ws, b2, b3, b4, ew, out);
}